// Round 2
// baseline (511.456 us; speedup 1.0000x reference)
//
#include <hip/hip_runtime.h>

#define LL 2048
#define DD 128
#define NB 32
#define KC 64
#define QB 128
#define NCH (LL / KC)
#define VP 72
#define SCALE 0.08838834764831845f

typedef short short8 __attribute__((ext_vector_type(8)));
typedef short short4v __attribute__((ext_vector_type(4)));
typedef float f32x4 __attribute__((ext_vector_type(4)));

__device__ __forceinline__ unsigned short f2bf(float f) {
  unsigned int u = __float_as_uint(f);
  u += 0x7fffu + ((u >> 16) & 1u);   // RNE
  return (unsigned short)(u >> 16);
}
__device__ __forceinline__ float bf2f(unsigned short s) {
  return __uint_as_float(((unsigned int)s) << 16);
}

__global__ __launch_bounds__(512, 4) void attn_fused(
    const float* __restrict__ q, const float* __restrict__ k,
    const float* __restrict__ v, float* __restrict__ out) {
  __shared__ __align__(16) unsigned short kT[KC * DD];      // 16 KB, XOR-swizzled
  __shared__ __align__(16) unsigned short vT[DD * VP];      // 18 KB, V transposed, padded
  __shared__ __align__(16) unsigned short pb[8][16 * KC];   // 16 KB, per-wave P

  const int tid = threadIdx.x;
  const int w = tid >> 6, l = tid & 63, lg = l >> 4, lr = l & 15;
  const int b = blockIdx.y;
  const int qw = blockIdx.x * QB + w * 16;

  const float* qb_ = q + (size_t)b * LL * DD;
  const float* kb_ = k + (size_t)b * LL * DD;
  const float* vb_ = v + (size_t)b * LL * DD;
  float* ctx  = out + ((size_t)b * LL + qw) * DD;
  float* attn = out + (size_t)NB * LL * DD + ((size_t)b * LL + qw) * (size_t)LL;

  // staging index maps
  const int kr  = tid >> 5, kc4 = tid & 31;            // K: rows kr+16i, col-group kc4
  const unsigned kswz = (kr & 7) << 3;
  const int vr0 = (tid & 15) * 4, vc0 = (tid >> 4) * 4; // V: 4x4 tile

  // ---- Q fragments: lane holds Q[qw+lr][dt*32 + lg*8 + j] ----
  short8 aq[4];
  {
    const float* qrow = qb_ + (size_t)(qw + lr) * DD + lg * 8;
#pragma unroll
    for (int dt = 0; dt < 4; ++dt) {
      f32x4 x0 = *(const f32x4*)(qrow + dt * 32);
      f32x4 x1 = *(const f32x4*)(qrow + dt * 32 + 4);
      short8 a;
#pragma unroll
      for (int j = 0; j < 4; ++j) { a[j] = (short)f2bf(x0[j]); a[4 + j] = (short)f2bf(x1[j]); }
      aq[dt] = a;
    }
  }

  f32x4 pk[4];
  float lsum[4] = {0.f, 0.f, 0.f, 0.f};

  // =================== pass 1: softmax denominators ===================
#pragma unroll
  for (int i = 0; i < 4; ++i)
    pk[i] = *(const f32x4*)(kb_ + (size_t)(kr + i * 16) * DD + kc4 * 4);
#pragma unroll
  for (int i = 0; i < 4; ++i) {
    f32x4 x = pk[i]; short4v y;
#pragma unroll
    for (int j = 0; j < 4; ++j) y[j] = (short)f2bf(x[j]);
    *(short4v*)&kT[((kr + i * 16) * 128 + kc4 * 4) ^ kswz] = y;
  }

  for (int kc = 0; kc < NCH; ++kc) {
    __syncthreads();
    if (kc + 1 < NCH) {
#pragma unroll
      for (int i = 0; i < 4; ++i)
        pk[i] = *(const f32x4*)(kb_ + (size_t)((kc + 1) * KC + kr + i * 16) * DD + kc4 * 4);
    }
    __builtin_amdgcn_s_setprio(1);
#pragma unroll
    for (int kt = 0; kt < 4; ++kt) {
      f32x4 acc = {0.f, 0.f, 0.f, 0.f};
      const int row = kt * 16 + lr;
      const unsigned sw = (row & 7) << 3;
#pragma unroll
      for (int dt = 0; dt < 4; ++dt) {
        short8 bk = *(const short8*)&kT[(row * 128 + dt * 32 + lg * 8) ^ sw];
        acc = __builtin_amdgcn_mfma_f32_16x16x32_bf16(aq[dt], bk, acc, 0, 0, 0);
      }
#pragma unroll
      for (int r = 0; r < 4; ++r) lsum[r] += __expf(acc[r] * SCALE);
    }
    __builtin_amdgcn_s_setprio(0);
    __syncthreads();
    if (kc + 1 < NCH) {
#pragma unroll
      for (int i = 0; i < 4; ++i) {
        f32x4 x = pk[i]; short4v y;
#pragma unroll
        for (int j = 0; j < 4; ++j) y[j] = (short)f2bf(x[j]);
        *(short4v*)&kT[((kr + i * 16) * 128 + kc4 * 4) ^ kswz] = y;
      }
    }
  }
#pragma unroll
  for (int r = 0; r < 4; ++r) {
    float s = lsum[r];
    s += __shfl_xor(s, 1); s += __shfl_xor(s, 2);
    s += __shfl_xor(s, 4); s += __shfl_xor(s, 8);
    lsum[r] = 1.0f / s;
  }

  // =================== pass 2: attn write + PV ===================
  f32x4 pv4[4];
  f32x4 apv[8];
#pragma unroll
  for (int dt = 0; dt < 8; ++dt) apv[dt] = (f32x4){0.f, 0.f, 0.f, 0.f};

#pragma unroll
  for (int i = 0; i < 4; ++i) {
    pk[i]  = *(const f32x4*)(kb_ + (size_t)(kr + i * 16) * DD + kc4 * 4);
    pv4[i] = *(const f32x4*)(vb_ + (size_t)(vr0 + i) * DD + vc0);
  }
#pragma unroll
  for (int i = 0; i < 4; ++i) {
    f32x4 x = pk[i]; short4v y;
#pragma unroll
    for (int j = 0; j < 4; ++j) y[j] = (short)f2bf(x[j]);
    *(short4v*)&kT[((kr + i * 16) * 128 + kc4 * 4) ^ kswz] = y;
  }
#pragma unroll
  for (int j = 0; j < 4; ++j) {
    short4v y = {(short)f2bf(pv4[0][j]), (short)f2bf(pv4[1][j]),
                 (short)f2bf(pv4[2][j]), (short)f2bf(pv4[3][j])};
    *(short4v*)&vT[(vc0 + j) * VP + vr0] = y;
  }

  for (int kc = 0; kc < NCH; ++kc) {
    __syncthreads();
    if (kc + 1 < NCH) {
#pragma unroll
      for (int i = 0; i < 4; ++i) {
        pk[i]  = *(const f32x4*)(kb_ + (size_t)((kc + 1) * KC + kr + i * 16) * DD + kc4 * 4);
        pv4[i] = *(const f32x4*)(vb_ + (size_t)((kc + 1) * KC + vr0 + i) * DD + vc0);
      }
    }

    // ---- QK^T + exp + stash P (bf16) in per-wave LDS ----
    __builtin_amdgcn_s_setprio(1);
#pragma unroll
    for (int kt = 0; kt < 4; ++kt) {
      f32x4 acc = {0.f, 0.f, 0.f, 0.f};
      const int row = kt * 16 + lr;
      const unsigned sw = (row & 7) << 3;
#pragma unroll
      for (int dt = 0; dt < 4; ++dt) {
        short8 bk = *(const short8*)&kT[(row * 128 + dt * 32 + lg * 8) ^ sw];
        acc = __builtin_amdgcn_mfma_f32_16x16x32_bf16(aq[dt], bk, acc, 0, 0, 0);
      }
#pragma unroll
      for (int r = 0; r < 4; ++r) {
        float p = __expf(acc[r] * SCALE) * lsum[r];
        const int qr = lg * 4 + r;
        pb[w][(qr * KC + kt * 16 + lr) ^ ((qr & 7) << 3)] = f2bf(p);
      }
    }
    __builtin_amdgcn_s_setprio(0);

    // ---- A-fragments for PV (wave-internal LDS dependency) ----
    short8 ap0 = *(const short8*)&pb[w][(lr * KC + lg * 8) ^ ((lr & 7) << 3)];
    short8 ap1 = *(const short8*)&pb[w][(lr * KC + 32 + lg * 8) ^ ((lr & 7) << 3)];

    // ---- coalesced attn store: 16 bf16/lane -> 4 dwordx4 ----
    {
      const int row = l >> 2, cb = (l & 3) * 16;
      const unsigned sw = (row & 7) << 3;
      short8 s0 = *(const short8*)&pb[w][(row * KC + cb) ^ sw];
      short8 s1 = *(const short8*)&pb[w][(row * KC + cb + 8) ^ sw];
      float* dst = attn + (size_t)row * LL + kc * KC + cb;
      f32x4 o0, o1, o2, o3;
#pragma unroll
      for (int j = 0; j < 4; ++j) {
        o0[j] = bf2f((unsigned short)s0[j]);
        o1[j] = bf2f((unsigned short)s0[4 + j]);
        o2[j] = bf2f((unsigned short)s1[j]);
        o3[j] = bf2f((unsigned short)s1[4 + j]);
      }
      *(f32x4*)(dst)      = o0;
      *(f32x4*)(dst + 4)  = o1;
      *(f32x4*)(dst + 8)  = o2;
      *(f32x4*)(dst + 12) = o3;
    }

    // ---- PV ----
    __builtin_amdgcn_s_setprio(1);
#pragma unroll
    for (int dt = 0; dt < 8; ++dt) {
      const int vrow = dt * 16 + lr;
      short8 b0 = *(const short8*)&vT[vrow * VP + lg * 8];
      short8 b1 = *(const short8*)&vT[vrow * VP + 32 + lg * 8];
      apv[dt] = __builtin_amdgcn_mfma_f32_16x16x32_bf16(ap0, b0, apv[dt], 0, 0, 0);
      apv[dt] = __builtin_amdgcn_mfma_f32_16x16x32_bf16(ap1, b1, apv[dt], 0, 0, 0);
    }
    __builtin_amdgcn_s_setprio(0);

    __syncthreads();
    if (kc + 1 < NCH) {
#pragma unroll
      for (int i = 0; i < 4; ++i) {
        f32x4 x = pk[i]; short4v y;
#pragma unroll
        for (int j = 0; j < 4; ++j) y[j] = (short)f2bf(x[j]);
        *(short4v*)&kT[((kr + i * 16) * 128 + kc4 * 4) ^ kswz] = y;
      }
#pragma unroll
      for (int j = 0; j < 4; ++j) {
        short4v y = {(short)f2bf(pv4[0][j]), (short)f2bf(pv4[1][j]),
                     (short)f2bf(pv4[2][j]), (short)f2bf(pv4[3][j])};
        *(short4v*)&vT[(vc0 + j) * VP + vr0] = y;
      }
    }
  }

  // ---- context store ----
#pragma unroll
  for (int dt = 0; dt < 8; ++dt)
#pragma unroll
    for (int r = 0; r < 4; ++r)
      ctx[(size_t)(lg * 4 + r) * DD + dt * 16 + lr] = apv[dt][r];
}

extern "C" void kernel_launch(void* const* d_in, const int* in_sizes, int n_in,
                              void* d_out, int out_size, void* d_ws, size_t ws_size,
                              hipStream_t stream) {
  const float* q = (const float*)d_in[0];
  const float* k = (const float*)d_in[1];
  const float* v = (const float*)d_in[2];
  float* out = (float*)d_out;
  dim3 grid(LL / QB, NB);
  dim3 block(512);
  attn_fused<<<grid, block, 0, stream>>>(q, k, v, out);
}